// Round 20
// baseline (48.436 us; speedup 1.0000x reference)
//
#include <hip/hip_runtime.h>
#include <hip/hip_fp16.h>

#define W 256
#define NA 180
#define SPLIT 4
#define RWORDS 145            // words per row; odd stride -> axis walks spread over banks
#define ROWBYTES 580
#define ROWS 259              // data rows 1..256 (pixel y + 1); data cols (halfs) 2..257 (pixel x + 2)

__global__ __launch_bounds__(1024, 4) void radon_kernel(
    const float* __restrict__ x, const int* __restrict__ index_p,
    float* __restrict__ out)
{
    __shared__ unsigned sw[ROWS * RWORDS];   // 150,220 B

    const int a = blockIdx.x;        // angle 0..179
    const int n = blockIdx.y;        // batch
    const int tid = threadIdx.x;
    const int c = tid & (W - 1);     // column 0..255
    const int s = tid >> 8;          // r-chunk 0..3 (wave-uniform)

    const float* __restrict__ img = x + (size_t)n * W * W;

    // ---- guard zero-fill (cells disjoint from staged data -> one barrier total) ----
    if (tid < 435) {                       // rows 0,257,258: 3 x 145 words
        const int rr = tid / 145;
        const int w = tid - rr * 145;
        const int row = (rr == 0) ? 0 : (256 + rr);
        sw[row * RWORDS + w] = 0u;
    } else if (tid < 947) {                // col guard words 0,129 rows 1..256
        const int i = tid - 435;
        const int row = 1 + (i >> 1);
        const int w = (i & 1) ? 129 : 0;
        sw[row * RWORDS + w] = 0u;
    }

    // ---- stage image -> LDS fp16 ----
    {
        const float4* img4 = (const float4*)img;
        #pragma unroll
        for (int k = 0; k < 16; ++k) {
            const int g = k * 1024 + tid;
            const int row = (g >> 6) + 1;      // 1..256
            const int m = g & 63;
            const float4 v = img4[g];
            const __half2 h01 = __floats2half2_rn(v.x, v.y);
            const __half2 h23 = __floats2half2_rn(v.z, v.w);
            sw[row * RWORDS + 2 * m + 1] = *(const unsigned*)&h01;  // halfs 4m+2,4m+3
            sw[row * RWORDS + 2 * m + 2] = *(const unsigned*)&h23;
        }
    }
    __syncthreads();

    const int index = *index_p;
    const int seg[6] = {1, 26, 51, 77, 102, 128};
    const int t0 = seg[4 - index];
    const int t1 = seg[4 - index + 1];

    float sa, ca;
    sincosf((float)a * 0.017453292519943295f, &sa, &ca);

    const float xc = ((2.0f * (float)c + 1.0f) * (1.0f / (float)W)) - 1.0f;
    const float bx = fmaf(128.0f * ca, xc, 129.5f);   // +2 x bias (halfs)
    const float by = fmaf(-128.0f * sa, xc, 128.5f);  // +1 y bias (rows)

    const int r1lo = 128 - t1;
    const int r0lo = 128 - t0, r0hi = 127 + t0;
    const int total = 2 * t1;
    const int chunk = (total + SPLIT - 1) / SPLIT;
    const int rs = r1lo + s * chunk;
    const int re = min(rs + chunk, r1lo + total);
    const int len = re - rs;               // wave-uniform, >= 13
    const int w0 = r0hi - r0lo;
    const int base0 = rs - r0lo;           // k + base0 in [0,w0] -> inner mask

    float sum0 = 0.0f, sum1 = 0.0f;

    // ---- depth-3 rotating software pipeline ----
    float wxA, wyA; int shA, adA; unsigned long long qAA, qBA;
    float wxB, wyB; int shB, adB; unsigned long long qAB, qBB;
    float wxC, wyC; int shC, adC; unsigned long long qAC, qBC;

    // STG: junk rf beyond range is med3-clamped into guard cells -> safe reads
#define STG(WX, WY, SH, AD, RF) {                                             \
        float ix = fmaf(sa, RF, bx);                                          \
        float iy = fmaf(ca, RF, by);                                          \
        ix = __builtin_amdgcn_fmed3f(ix, 1.0f, 258.0f);                       \
        iy = __builtin_amdgcn_fmed3f(iy, 0.0f, 257.0f);                       \
        WX = __builtin_amdgcn_fractf(ix);                                     \
        WY = __builtin_amdgcn_fractf(iy);                                     \
        const int x0 = (int)ix;                                               \
        const int y0 = (int)iy;                                               \
        SH = (x0 & 1) << 4;                                                   \
        AD = y0 * ROWBYTES + (x0 >> 1) * 4; }

#define ISS(QA, QB, AD)                                                       \
        asm volatile("ds_read2_b32 %0, %2 offset0:0 offset1:145\n\t"          \
                     "ds_read2_b32 %1, %2 offset0:1 offset1:146"              \
                     : "=&v"(QA), "=&v"(QB) : "v"(AD));

    // CNS(k): wait keeps <=2 newer pairs outstanding (correct for 1- or
    // 2-count ds_read2 lgkm semantics); masks are wave-uniform scalars.
#define CNS(QA, QB, WX, WY, SH, K) {                                          \
        asm volatile("s_waitcnt lgkmcnt(4)" : "+v"(QA), "+v"(QB));            \
        const unsigned A0 = (unsigned)QA, A1 = (unsigned)(QA >> 32);          \
        const unsigned B0 = (unsigned)QB, B1 = (unsigned)(QB >> 32);          \
        const unsigned q0 = __builtin_amdgcn_alignbit(B0, A0, SH);            \
        const unsigned q1 = __builtin_amdgcn_alignbit(B1, A1, SH);            \
        const __half2 h0 = *(const __half2*)&q0;                              \
        const __half2 h1 = *(const __half2*)&q1;                              \
        const __half2 wy2 = __float2half2_rn(WY);                             \
        const __half2 t = __hfma2(wy2, __hsub2(h1, h0), h0);                  \
        const float tl = __low2float(t);                                      \
        const float th = __high2float(t);                                     \
        const float val = fmaf(WX, th - tl, tl);                              \
        const bool m1 = (K) < len;                                            \
        const bool m0 = m1 && ((unsigned)((K) + base0) <= (unsigned)w0);      \
        sum1 += m1 ? val : 0.0f;                                              \
        sum0 += m0 ? val : 0.0f; }

    const float rf0 = (float)rs - 127.5f;
    float rfA = rf0, rfB = rf0 + 1.0f, rfC = rf0 + 2.0f;

    STG(wxA, wyA, shA, adA, rfA) ISS(qAA, qBA, adA) rfA += 3.0f;
    STG(wxB, wyB, shB, adB, rfB) ISS(qAB, qBB, adB) rfB += 3.0f;
    STG(wxC, wyC, shC, adC, rfC) ISS(qAC, qBC, adC) rfC += 3.0f;

    for (int k0 = 0; k0 < len; k0 += 3) {
        CNS(qAA, qBA, wxA, wyA, shA, k0)
        STG(wxA, wyA, shA, adA, rfA) ISS(qAA, qBA, adA) rfA += 3.0f;
        CNS(qAB, qBB, wxB, wyB, shB, k0 + 1)
        STG(wxB, wyB, shB, adB, rfB) ISS(qAB, qBB, adB) rfB += 3.0f;
        CNS(qAC, qBC, wxC, wyC, shC, k0 + 2)
        STG(wxC, wyC, shC, adC, rfC) ISS(qAC, qBC, adC) rfC += 3.0f;
    }
    // drain the 3 outstanding junk pairs before LDS is reused
    asm volatile("s_waitcnt lgkmcnt(0)"
                 : "+v"(qAA), "+v"(qBA), "+v"(qAB), "+v"(qBB), "+v"(qAC), "+v"(qBC));

#undef STG
#undef ISS
#undef CNS

    // ---- reduce partials; reuse sw as scratch ----
    __syncthreads();
    float* red = (float*)sw;                 // 8 KB of 150 KB
    red[(0 * SPLIT + s) * W + c] = sum0;
    red[(1 * SPLIT + s) * W + c] = sum1;
    __syncthreads();

    if (s == 0) {
        const float acc0 = red[0 * W + c] + red[1 * W + c] + red[2 * W + c] + red[3 * W + c];
        const float* r1p = red + SPLIT * W;
        const float acc1 = r1p[0 * W + c] + r1p[1 * W + c] + r1p[2 * W + c] + r1p[3 * W + c];
        out[(((size_t)n * 2 + 0) * W + c) * NA + a] = acc0 * (1.0f / (float)(2 * t0));
        out[(((size_t)n * 2 + 1) * W + c) * NA + a] = acc1 * (1.0f / (float)(2 * t1));
    }
}

extern "C" void kernel_launch(void* const* d_in, const int* in_sizes, int n_in,
                              void* d_out, int out_size, void* d_ws, size_t ws_size,
                              hipStream_t stream) {
    const float* x = (const float*)d_in[0];
    const int* index_p = (const int*)d_in[1];
    float* out = (float*)d_out;
    const int N = in_sizes[0] / (W * W); // 4
    dim3 grid(NA, N);
    radon_kernel<<<grid, 1024, 0, stream>>>(x, index_p, out);
}